// Round 2
// baseline (795.598 us; speedup 1.0000x reference)
//
#include <hip/hip_runtime.h>
#include <stdint.h>
#include <stddef.h>

// ---------------------------------------------------------------------------
// StarBlock on MI355X — round 2: 8-phase 256^2 counted-vmcnt up-GEMM.
//   * x split IN-PLACE (d_in[0]) into per-row [hi(1024)|lo(1024)] bf16.
//   * up GEMM: C[32768x4096] = xsplit @ wcat^T, K=2048 (hi tiles 0-15,
//     lo tiles 16-31 share weight cols via t&15). wcat rows interleave
//     w1/w2 (n=2c+g) so epilogue pairing is lane-local (shfl_xor 1,2).
//   * epilogue: bias/relu/floorq/pair-product-sum/floorq -> h int8 (exact).
//   * down: i8 MFMA 16x16x64 (integer-exact), unchanged from round 1.
// ---------------------------------------------------------------------------

#define KDIN  1024
#define NTOT  4096
#define HCOLS 1024
#define NOUT  1024
#define NKT   32      // K-tiles of 64 over K=2048

typedef __attribute__((ext_vector_type(4))) float    f32x4;
typedef __attribute__((ext_vector_type(4))) int      i32x4;
typedef __attribute__((ext_vector_type(8))) __bf16   bf16x8;
typedef __attribute__((ext_vector_type(8))) uint16_t u16x8;

typedef const __attribute__((address_space(1))) void* gas_ptr;
typedef __attribute__((address_space(3))) void*       las_ptr;

__device__ __forceinline__ void gload16(const void* g, void* l) {
  __builtin_amdgcn_global_load_lds((gas_ptr)(uintptr_t)g,
                                   (las_ptr)(uint32_t)(uintptr_t)l, 16, 0, 0);
}

__device__ __forceinline__ uint16_t f32_bf16_rn(float f) {
  uint32_t u = __float_as_uint(f);
  return (uint16_t)((u + 0x7FFFu + ((u >> 16) & 1u)) >> 16);
}

// ---------------------------- prep kernels ---------------------------------

// in-place: row of 1024 f32 -> [1024 hi bf16 | 1024 lo bf16] (same 4KB)
__global__ void split_x_kernel(float* __restrict__ x) {
  float* row = x + ((size_t)blockIdx.x << 10);
  float4 v = reinterpret_cast<float4*>(row)[threadIdx.x];
  ushort4 hi, lo;
  {
    uint32_t b;
    b = __float_as_uint(v.x); hi.x = b >> 16;
    lo.x = (uint16_t)(__float_as_uint(v.x - __uint_as_float(b & 0xFFFF0000u)) >> 16);
    b = __float_as_uint(v.y); hi.y = b >> 16;
    lo.y = (uint16_t)(__float_as_uint(v.y - __uint_as_float(b & 0xFFFF0000u)) >> 16);
    b = __float_as_uint(v.z); hi.z = b >> 16;
    lo.z = (uint16_t)(__float_as_uint(v.z - __uint_as_float(b & 0xFFFF0000u)) >> 16);
    b = __float_as_uint(v.w); hi.w = b >> 16;
    lo.w = (uint16_t)(__float_as_uint(v.w - __uint_as_float(b & 0xFFFF0000u)) >> 16);
  }
  __syncthreads();
  ushort4* ru = reinterpret_cast<ushort4*>(row);
  ru[threadIdx.x] = hi;
  ru[256 + threadIdx.x] = lo;
}

// wcat[4096][1024] bf16, row n = quantized (n&1 ? w2 : w1) row (n>>1)
__global__ void wcat_kernel(const float* __restrict__ w1,
                            const float* __restrict__ w2,
                            uint16_t* __restrict__ wc) {
  int idx = blockIdx.x * blockDim.x + threadIdx.x;   // 1M float4 chunks
  int n = idx >> 8, kq = idx & 255;
  const float* src = ((n & 1) ? w2 : w1) + (((size_t)(n >> 1)) << 10) + (kq << 2);
  float4 v = *reinterpret_cast<const float4*>(src);
  ushort4 o;
  o.x = f32_bf16_rn(rintf(fminf(fmaxf(v.x * 128.f, -128.f), 127.f)) * 0.0078125f);
  o.y = f32_bf16_rn(rintf(fminf(fmaxf(v.y * 128.f, -128.f), 127.f)) * 0.0078125f);
  o.z = f32_bf16_rn(rintf(fminf(fmaxf(v.z * 128.f, -128.f), 127.f)) * 0.0078125f);
  o.w = f32_bf16_rn(rintf(fminf(fmaxf(v.w * 128.f, -128.f), 127.f)) * 0.0078125f);
  reinterpret_cast<ushort4*>(wc)[idx] = o;
}

__global__ void bcat_kernel(const float* __restrict__ b1,
                            const float* __restrict__ b2,
                            float* __restrict__ bc) {
  int n = blockIdx.x * blockDim.x + threadIdx.x;
  if (n < NTOT) {
    float v = (n & 1) ? b2[n >> 1] : b1[n >> 1];
    bc[n] = rintf(v * 16384.f) * (1.f / 16384.f);
  }
}

__global__ void quant_w_i8_kernel(const float* __restrict__ in,
                                  int8_t* __restrict__ out, int n4) {
  int stride = gridDim.x * blockDim.x;
  for (int i = blockIdx.x * blockDim.x + threadIdx.x; i < n4; i += stride) {
    float4 v = reinterpret_cast<const float4*>(in)[i];
    char4 o;
    o.x = (int8_t)(int)rintf(fminf(fmaxf(v.x * 128.f, -128.f), 127.f));
    o.y = (int8_t)(int)rintf(fminf(fmaxf(v.y * 128.f, -128.f), 127.f));
    o.z = (int8_t)(int)rintf(fminf(fmaxf(v.z * 128.f, -128.f), 127.f));
    o.w = (int8_t)(int)rintf(fminf(fmaxf(v.w * 128.f, -128.f), 127.f));
    reinterpret_cast<char4*>(out)[i] = o;
  }
}

__global__ void quant_b_kernel(const float* __restrict__ in,
                               float* __restrict__ out, int n) {
  int i = blockIdx.x * blockDim.x + threadIdx.x;
  if (i < n) out[i] = rintf(in[i] * 16384.f) * (1.f / 16384.f);
}

// ------------------------- staging / fragments -----------------------------
// bf16 tiles: 128 rows x 64 cols per half; row = 128B = 8 slots of 16B.
// Invariant: LDS[row][slot p] holds global slot p ^ (row&7).

__device__ __forceinline__ void stage_half_b16(const uint16_t* g, int gld,
                                               uint16_t* lds, int wid, int lane) {
  int rl = lane >> 3, s = lane & 7;
  int gs = s ^ rl;                          // row&7 == rl (chunks are 8-row aligned)
#pragma unroll
  for (int i = 0; i < 2; ++i) {
    int chunk = wid * 2 + i;
    gload16(g + (size_t)(chunk * 8 + rl) * gld + (gs << 3), lds + (chunk << 9));
  }
}

__device__ __forceinline__ bf16x8 fragr(const uint16_t* lds, int tr, int g) {
  int off = (tr << 6) + ((g ^ (tr & 7)) << 3);
  return __builtin_bit_cast(bf16x8, *reinterpret_cast<const u16x8*>(lds + off));
}

// i8 tile helpers (down kernel, unchanged from round 1)
template <int CNT>
__device__ __forceinline__ void stage_i8_tile(const int8_t* g, int8_t* lds,
                                              int lane, int c0) {
  int rl = lane >> 2, s = lane & 3;
#pragma unroll
  for (int i = 0; i < CNT; ++i) {
    int c = c0 + i;
    int r = (c << 4) + rl;
    int gs = s ^ (rl & 3);
    gload16(g + (size_t)r * (size_t)HCOLS + (gs << 4), lds + (c << 10));
  }
}

__device__ __forceinline__ i32x4 frag_i8(const int8_t* lds, int tr, int g) {
  int off = (tr << 6) + ((g ^ (tr & 3)) << 4);
  return *reinterpret_cast<const i32x4*>(lds + off);
}

// ------------------------------ up kernel ----------------------------------
// 8-phase 256x256 template: 512 thr (8 waves 2Mx4N), BK=64, 128KB LDS dbuf.
// LDS buf b (b*32768 elems): A 256x64 at +0, B 256x64 at +16384.
// Half-tiles: h0=A rows 0-127, h1=A 128-255, h2=B 0-127, h3=B 128-255.
// Per K-tile t: p0{ds A-mlo+B-nlo; stage(t+1,h1)} p1{ds B-nhi; stage(t+1,h2)}
// p2{ds A-mhi; stage(t+1,h3)} p3{stage(t+2,h0); vmcnt(2)} — never vmcnt(0)
// in steady state; tile t+1's halves (issued >=4 phases earlier) are drained
// by p3's vmcnt(2) which allows only the (t+2,h0) pair outstanding.

template <int B, bool S1, bool S2, int VMC>
__device__ __forceinline__ void ktile_body(
    int t, const uint16_t* __restrict__ Ab, const uint16_t* __restrict__ Bb,
    uint16_t* lds, int wid, int lane, int wr, int wn, int lrow, int kg,
    f32x4 (&acc)[8][4]) {
  uint16_t* As0 = lds + B * 32768;
  uint16_t* Bs0 = As0 + 16384;
  uint16_t* AsN = lds + (B ^ 1) * 32768;
  uint16_t* BsN = AsN + 16384;
  const uint16_t* An = Ab + (t + 1) * 64;          // A col base, tile t+1
  const uint16_t* Bn = Bb + ((t + 1) & 15) * 64;   // B col base (k mod 1024)

  bf16x8 alo[8], ahi[8], blo[4], bhi[4];

  // ---- phase 0 ----
#pragma unroll
  for (int mf = 0; mf < 4; ++mf)
#pragma unroll
    for (int ks = 0; ks < 2; ++ks)
      alo[mf * 2 + ks] = fragr(As0, wr * 128 + mf * 16 + lrow, ks * 4 + kg);
#pragma unroll
  for (int nf = 0; nf < 2; ++nf)
#pragma unroll
    for (int ks = 0; ks < 2; ++ks)
      blo[nf * 2 + ks] = fragr(Bs0, wn * 64 + nf * 16 + lrow, ks * 4 + kg);
  if (S1) stage_half_b16(An + (size_t)128 * 2048, 2048, AsN + 8192, wid, lane);
  __builtin_amdgcn_s_barrier();
  asm volatile("s_waitcnt lgkmcnt(0)");
  __builtin_amdgcn_s_setprio(1);
#pragma unroll
  for (int mf = 0; mf < 4; ++mf)
#pragma unroll
    for (int nf = 0; nf < 2; ++nf)
#pragma unroll
      for (int ks = 0; ks < 2; ++ks)
        acc[mf][nf] = __builtin_amdgcn_mfma_f32_16x16x32_bf16(
            alo[mf * 2 + ks], blo[nf * 2 + ks], acc[mf][nf], 0, 0, 0);
  __builtin_amdgcn_s_setprio(0);
  __builtin_amdgcn_s_barrier();

  // ---- phase 1 ----
#pragma unroll
  for (int nf = 0; nf < 2; ++nf)
#pragma unroll
    for (int ks = 0; ks < 2; ++ks)
      bhi[nf * 2 + ks] = fragr(Bs0, wn * 64 + (nf + 2) * 16 + lrow, ks * 4 + kg);
  if (S1) stage_half_b16(Bn, 1024, BsN, wid, lane);
  __builtin_amdgcn_s_barrier();
  asm volatile("s_waitcnt lgkmcnt(0)");
  __builtin_amdgcn_s_setprio(1);
#pragma unroll
  for (int mf = 0; mf < 4; ++mf)
#pragma unroll
    for (int nf = 0; nf < 2; ++nf)
#pragma unroll
      for (int ks = 0; ks < 2; ++ks)
        acc[mf][nf + 2] = __builtin_amdgcn_mfma_f32_16x16x32_bf16(
            alo[mf * 2 + ks], bhi[nf * 2 + ks], acc[mf][nf + 2], 0, 0, 0);
  __builtin_amdgcn_s_setprio(0);
  __builtin_amdgcn_s_barrier();

  // ---- phase 2 ----
#pragma unroll
  for (int mf = 0; mf < 4; ++mf)
#pragma unroll
    for (int ks = 0; ks < 2; ++ks)
      ahi[mf * 2 + ks] = fragr(As0, wr * 128 + (mf + 4) * 16 + lrow, ks * 4 + kg);
  if (S1) stage_half_b16(Bn + (size_t)128 * 1024, 1024, BsN + 8192, wid, lane);
  __builtin_amdgcn_s_barrier();
  asm volatile("s_waitcnt lgkmcnt(0)");
  __builtin_amdgcn_s_setprio(1);
#pragma unroll
  for (int mf = 0; mf < 4; ++mf)
#pragma unroll
    for (int nf = 0; nf < 2; ++nf)
#pragma unroll
      for (int ks = 0; ks < 2; ++ks)
        acc[mf + 4][nf] = __builtin_amdgcn_mfma_f32_16x16x32_bf16(
            ahi[mf * 2 + ks], blo[nf * 2 + ks], acc[mf + 4][nf], 0, 0, 0);
  __builtin_amdgcn_s_setprio(0);
  __builtin_amdgcn_s_barrier();

  // ---- phase 3 ----
  if (S2) stage_half_b16(Ab + (t + 2) * 64, 2048, As0, wid, lane);
  __builtin_amdgcn_s_barrier();
  __builtin_amdgcn_s_setprio(1);
#pragma unroll
  for (int mf = 0; mf < 4; ++mf)
#pragma unroll
    for (int nf = 0; nf < 2; ++nf)
#pragma unroll
      for (int ks = 0; ks < 2; ++ks)
        acc[mf + 4][nf + 2] = __builtin_amdgcn_mfma_f32_16x16x32_bf16(
            ahi[mf * 2 + ks], bhi[nf * 2 + ks], acc[mf + 4][nf + 2], 0, 0, 0);
  __builtin_amdgcn_s_setprio(0);
  if (VMC == 2)      asm volatile("s_waitcnt vmcnt(2)" ::: "memory");
  else if (VMC == 0) asm volatile("s_waitcnt vmcnt(0)" ::: "memory");
  __builtin_amdgcn_s_barrier();
}

__global__ __launch_bounds__(512, 2)
void up8_kernel(const uint16_t* __restrict__ xs, const uint16_t* __restrict__ wc,
                const float* __restrict__ bcat, int8_t* __restrict__ hbuf) {
  __shared__ alignas(16) uint16_t lds[65536];   // 128 KB

  const int tid = threadIdx.x, lane = tid & 63, wid = tid >> 6;
  const int bid = blockIdx.x;
  const int swz = ((bid & 7) << 8) | (bid >> 3);   // 2048 % 8 == 0: bijective
  const int bm = swz >> 4, bn = swz & 15;
  const size_t row0 = (size_t)bm << 8;
  const int ncol0 = bn << 8;

  const int wr = wid >> 2, wn = wid & 3;
  const int lrow = lane & 15, kg = lane >> 4;

  const uint16_t* Ab = xs + row0 * 2048;
  const uint16_t* Bb = wc + (size_t)ncol0 * 1024;

  f32x4 acc[8][4];
  const f32x4 z4 = {0.f, 0.f, 0.f, 0.f};
#pragma unroll
  for (int m = 0; m < 8; ++m)
#pragma unroll
    for (int n = 0; n < 4; ++n) acc[m][n] = z4;

  // prologue: tile0 h0-h3 + tile1 h0 (10 loads/thread); drain tile0 (keep 2)
  stage_half_b16(Ab, 2048, lds, wid, lane);
  stage_half_b16(Ab + (size_t)128 * 2048, 2048, lds + 8192, wid, lane);
  stage_half_b16(Bb, 1024, lds + 16384, wid, lane);
  stage_half_b16(Bb + (size_t)128 * 1024, 1024, lds + 24576, wid, lane);
  stage_half_b16(Ab + 64, 2048, lds + 32768, wid, lane);
  asm volatile("s_waitcnt vmcnt(2)" ::: "memory");
  __builtin_amdgcn_s_barrier();

#pragma unroll 1
  for (int tt = 0; tt < (NKT - 2) / 2; ++tt) {
    ktile_body<0, true, true, 2>(2 * tt,     Ab, Bb, lds, wid, lane, wr, wn, lrow, kg, acc);
    ktile_body<1, true, true, 2>(2 * tt + 1, Ab, Bb, lds, wid, lane, wr, wn, lrow, kg, acc);
  }
  ktile_body<0, true,  false, 0>(NKT - 2, Ab, Bb, lds, wid, lane, wr, wn, lrow, kg, acc);
  ktile_body<1, false, false, -1>(NKT - 1, Ab, Bb, lds, wid, lane, wr, wn, lrow, kg, acc);

  // epilogue: bias, per-parity quant, pair product (xor1), pair sum (xor2) -> i8
  const float* bc = bcat + ncol0 + wn * 64;
  const bool isX1 = !(lane & 1);
#pragma unroll
  for (int nf = 0; nf < 4; ++nf) {
    const int ncl = nf * 16 + lrow;
    const int gn = ncol0 + wn * 64 + ncl;
    const float bb = bc[ncl];
#pragma unroll
    for (int mf = 0; mf < 8; ++mf) {
      const size_t grow0 = row0 + wr * 128 + mf * 16 + (kg << 2);
#pragma unroll
      for (int j = 0; j < 4; ++j) {
        float v = acc[mf][nf][j] + bb;
        float q;
        if (isX1) q = floorf(fminf(fmaxf(v, 0.f) * 128.f, 127.f));
        else      q = floorf(fminf(fmaxf(v * 128.f, -128.f), 127.f));
        float p = q * __shfl_xor(q, 1, 64);
        float s = p + __shfl_xor(p, 2, 64);
        if (!(lane & 3)) {
          float hs = floorf(fminf(fmaxf(s * 0.0078125f, -128.f), 127.f));
          hbuf[(grow0 + j) * HCOLS + (gn >> 2)] = (int8_t)(int)hs;
        }
      }
    }
  }
}

// ----------------------------- down kernel ---------------------------------

__global__ __launch_bounds__(256, 2)
void down_kernel(const int8_t* __restrict__ hbuf, const int8_t* __restrict__ wdq,
                 const float* __restrict__ bdq, float* __restrict__ out) {
  __shared__ alignas(16) int8_t sA[128 * 64];
  __shared__ alignas(16) int8_t sB[128 * 64];

  const int tid = threadIdx.x, lane = tid & 63, wid = tid >> 6;
  const int bid = blockIdx.x;
  const int swz = ((bid & 7) << 8) | (bid >> 3);   // 2048 blocks, XCD-chunked
  const int bm = swz >> 3, bn = swz & 7;
  const size_t row0 = (size_t)bm * 128;
  const int    col0 = bn * 128;

  const int8_t* hbase = hbuf + row0 * HCOLS;
  const int8_t* wbase = wdq + (size_t)col0 * HCOLS;

  const i32x4 z4 = {0, 0, 0, 0};
  i32x4 acc[4][4];
#pragma unroll
  for (int m = 0; m < 4; ++m)
#pragma unroll
    for (int n = 0; n < 4; ++n) acc[m][n] = z4;

  const int wr = wid >> 1, wc = wid & 1;
  const int lrow = lane & 15, kg = lane >> 4;

  for (int t = 0; t < HCOLS / 64; ++t) {
    __syncthreads();
    if (wid < 2) stage_i8_tile<4>(hbase + t * 64, sA, lane, wid << 2);
    else         stage_i8_tile<4>(wbase + t * 64, sB, lane, (wid - 2) << 2);
    __syncthreads();

    i32x4 a[4], b[4];
#pragma unroll
    for (int m = 0; m < 4; ++m) a[m] = frag_i8(sA, (wr << 6) + (m << 4) + lrow, kg);
#pragma unroll
    for (int n = 0; n < 4; ++n) b[n] = frag_i8(sB, (wc << 6) + (n << 4) + lrow, kg);
#pragma unroll
    for (int m = 0; m < 4; ++m)
#pragma unroll
      for (int n = 0; n < 4; ++n)
        acc[m][n] = __builtin_amdgcn_mfma_i32_16x16x64_i8(a[m], b[n], acc[m][n], 0, 0, 0);
  }

#pragma unroll
  for (int n = 0; n < 4; ++n) {
    const int gc = col0 + (wc << 6) + (n << 4) + lrow;
    const float bb = bdq[gc];
#pragma unroll
    for (int m = 0; m < 4; ++m) {
      const size_t gr0 = row0 + (wr << 6) + (m << 4) + (kg << 2);
#pragma unroll
      for (int j = 0; j < 4; ++j)
        out[(gr0 + j) * NOUT + gc] =
            fmaxf((float)acc[m][n][j] * (1.f / 16384.f) + bb, 0.f);
    }
  }
}

// ------------------------------- launch ------------------------------------

extern "C" void kernel_launch(void* const* d_in, const int* in_sizes, int n_in,
                              void* d_out, int out_size, void* d_ws, size_t ws_size,
                              hipStream_t stream) {
  float* x        = (float*)d_in[0];   // rewritten in-place (restored by harness)
  const float* w1 = (const float*)d_in[1];
  const float* b1 = (const float*)d_in[2];
  const float* w2 = (const float*)d_in[3];
  const float* b2 = (const float*)d_in[4];
  const float* wd = (const float*)d_in[5];
  const float* bd = (const float*)d_in[6];
  float* out = (float*)d_out;

  // workspace layout (~41 MB; 43 MB proven available in round 1)
  char* ws = (char*)d_ws;
  uint16_t* wcat = (uint16_t*)(ws);                    // 8 MB
  int8_t*   hbuf = (int8_t*)(ws + 8388608);            // 32 MB
  int8_t*   wdq  = (int8_t*)(ws + 41943040);           // 1 MB
  float*    bcat = (float*)(ws + 42991616);            // 16 KB
  float*    bdq  = (float*)(ws + 43008000);            // 4 KB

  split_x_kernel<<<32768, 256, 0, stream>>>(x);
  wcat_kernel<<<4096, 256, 0, stream>>>(w1, w2, wcat);
  bcat_kernel<<<16, 256, 0, stream>>>(b1, b2, bcat);
  quant_w_i8_kernel<<<256, 256, 0, stream>>>(wd, wdq, NOUT * HCOLS / 4);
  quant_b_kernel<<<4, 256, 0, stream>>>(bd, bdq, NOUT);

  up8_kernel<<<2048, 512, 0, stream>>>((const uint16_t*)x, wcat, bcat, hbuf);
  down_kernel<<<2048, 256, 0, stream>>>(hbuf, wdq, bdq, out);
}